// Round 1
// baseline (628.632 us; speedup 1.0000x reference)
//
#include <hip/hip_runtime.h>
#include <cstddef>

// EGNN layer, fp32 correctness-first implementation.
// N=50000 nodes, M=800000 edges, H=64, E=16, IN_E=145.
//
// Decomposition:
//   K1 node_pre : hA = h @ w1e[1:65], hB = h @ w1e[65:129]   (per-node, reused ~16x per edge)
//   K2 edge     : pre1 = b1e + sq*w1e[0] + hA[row] + hB[col] + fea @ w1e[129:145]
//                 u1 = silu(pre1); msg = silu(u1@w2e + b2e)
//                 t = silu(msg@wc1 + bc1); coord = <t, wc2> + bc2
//                 atomicAdd msg into tot_msg[row], (rij*coord, 1) into totf4[row]
//   K3 node     : x_new = x + clamp(tot_f/max(deg,1), +-100)
//                 h_new = silu([h, tot_msg] @ wn1 + bn1) @ wn2 + bn2
//
// Wave layout: 4 waves/block, each wave processes 4 edges (or 4 nodes) at a
// time: lane j owns output channel j; activations staged per-wave in LDS and
// re-read as broadcast float4; weights staged once per block in LDS.
// Edge indices are wave-uniform (readfirstlane) so row/col/x/fea loads go
// through the scalar path.

#define N_NODES 50000
#define M_EDGES 800000

__device__ __forceinline__ float silu_f(float v) {
    return v / (1.0f + __expf(-v));
}

// ---------------------------------------------------------------- K1: hA/hB
__global__ __launch_bounds__(256) void node_pre_kernel(
    const float* __restrict__ h, const float* __restrict__ w1e,
    float* __restrict__ hA, float* __restrict__ hB)
{
    __shared__ __align__(16) float wa_s[64 * 64];
    __shared__ __align__(16) float wb_s[64 * 64];
    __shared__ __align__(16) float hs[4][4][64];

    const int tid  = threadIdx.x;
    const int lane = tid & 63;
    const int wv   = __builtin_amdgcn_readfirstlane(tid >> 6);

    {   // stage weights: w1e rows 1..64 -> wa, rows 65..128 -> wb
        const float4* sa = (const float4*)(w1e + 64);
        const float4* sb = (const float4*)(w1e + 65 * 64);
        float4* da = (float4*)wa_s;
        float4* db = (float4*)wb_s;
        for (int i = tid; i < 1024; i += 256) { da[i] = sa[i]; db[i] = sb[i]; }
    }
    const int n0 = blockIdx.x * 16 + wv * 4;
    #pragma unroll
    for (int nn = 0; nn < 4; ++nn)
        hs[wv][nn][lane] = h[(n0 + nn) * 64 + lane];
    __syncthreads();

    float accA[4] = {0.f, 0.f, 0.f, 0.f};
    float accB[4] = {0.f, 0.f, 0.f, 0.f};
    #pragma unroll
    for (int kg = 0; kg < 16; ++kg) {
        float hv[4][4];
        #pragma unroll
        for (int nn = 0; nn < 4; ++nn) {
            float4 v = *(const float4*)&hs[wv][nn][kg * 4];
            hv[nn][0] = v.x; hv[nn][1] = v.y; hv[nn][2] = v.z; hv[nn][3] = v.w;
        }
        #pragma unroll
        for (int i = 0; i < 4; ++i) {
            const float wa = wa_s[(kg * 4 + i) * 64 + lane];
            const float wb = wb_s[(kg * 4 + i) * 64 + lane];
            #pragma unroll
            for (int nn = 0; nn < 4; ++nn) {
                accA[nn] += hv[nn][i] * wa;
                accB[nn] += hv[nn][i] * wb;
            }
        }
    }
    #pragma unroll
    for (int nn = 0; nn < 4; ++nn) {
        hA[(n0 + nn) * 64 + lane] = accA[nn];
        hB[(n0 + nn) * 64 + lane] = accB[nn];
    }
}

// ---------------------------------------------------------------- K2: edges
__global__ __launch_bounds__(256) void edge_kernel(
    const float* __restrict__ x, const float* __restrict__ edge_fea,
    const float* __restrict__ w1e, const float* __restrict__ b1e,
    const float* __restrict__ w2e, const float* __restrict__ b2e,
    const float* __restrict__ wc1, const float* __restrict__ bc1,
    const float* __restrict__ wc2, const float* __restrict__ bc2,
    const int* __restrict__ row, const int* __restrict__ col,
    const float* __restrict__ hA, const float* __restrict__ hB,
    float* __restrict__ tot_msg, float* __restrict__ totf4)
{
    __shared__ __align__(16) float w1c_s[16 * 64];
    __shared__ __align__(16) float w2_s[64 * 64];
    __shared__ __align__(16) float wc1_s[64 * 64];
    __shared__ float b1_s[64], w1r0_s[64], b2_s[64], bc1_s[64], wc2_s[64];
    __shared__ __align__(16) float su_s[4][4][64];   // u1 staging per wave
    __shared__ __align__(16) float sm_s[4][4][64];   // msg staging per wave

    const int tid  = threadIdx.x;
    const int lane = tid & 63;
    const int wv   = __builtin_amdgcn_readfirstlane(tid >> 6);

    {
        const float4* s1 = (const float4*)(w1e + 129 * 64);
        float4* d1 = (float4*)w1c_s;
        for (int i = tid; i < 256; i += 256) d1[i] = s1[i];
        const float4* s2 = (const float4*)w2e;
        float4* d2 = (float4*)w2_s;
        const float4* s3 = (const float4*)wc1;
        float4* d3 = (float4*)wc1_s;
        for (int i = tid; i < 1024; i += 256) { d2[i] = s2[i]; d3[i] = s3[i]; }
        if (tid < 64) {
            b1_s[tid]   = b1e[tid];
            w1r0_s[tid] = w1e[tid];
            b2_s[tid]   = b2e[tid];
            bc1_s[tid]  = bc1[tid];
            wc2_s[tid]  = wc2[tid];
        }
    }
    __syncthreads();
    const float bc2v = bc2[0];

    for (int g = blockIdx.x; g < M_EDGES / 16; g += gridDim.x) {
        const int ebase = g * 16 + wv * 4;
        float rxa[4], rya[4], rza[4], cmsg[4];
        int ra[4];

        // ---- layer 1 (16-K GEMM + gathered adds), silu, stage u1
        #pragma unroll
        for (int ee = 0; ee < 4; ++ee) {
            const int e = ebase + ee;
            const int r = __builtin_amdgcn_readfirstlane(row[e]);
            const int c = __builtin_amdgcn_readfirstlane(col[e]);
            ra[ee] = r;
            const float dx = x[r * 3 + 0] - x[c * 3 + 0];
            const float dy = x[r * 3 + 1] - x[c * 3 + 1];
            const float dz = x[r * 3 + 2] - x[c * 3 + 2];
            rxa[ee] = dx; rya[ee] = dy; rza[ee] = dz;
            const float sq = dx * dx + dy * dy + dz * dz;
            float p = b1_s[lane] + sq * w1r0_s[lane];
            p += hA[r * 64 + lane];
            p += hB[c * 64 + lane];
            const float* ef = edge_fea + (size_t)e * 16;
            #pragma unroll
            for (int k = 0; k < 16; ++k)
                p += ef[k] * w1c_s[k * 64 + lane];
            su_s[wv][ee][lane] = silu_f(p);
        }

        // ---- layer 2: msg = silu(u1 @ w2e + b2e); atomic into tot_msg[row]
        float m[4] = {0.f, 0.f, 0.f, 0.f};
        #pragma unroll
        for (int kg = 0; kg < 16; ++kg) {
            float uv[4][4];
            #pragma unroll
            for (int ee = 0; ee < 4; ++ee) {
                float4 v = *(const float4*)&su_s[wv][ee][kg * 4];
                uv[ee][0] = v.x; uv[ee][1] = v.y; uv[ee][2] = v.z; uv[ee][3] = v.w;
            }
            #pragma unroll
            for (int i = 0; i < 4; ++i) {
                const float wvv = w2_s[(kg * 4 + i) * 64 + lane];
                #pragma unroll
                for (int ee = 0; ee < 4; ++ee) m[ee] += uv[ee][i] * wvv;
            }
        }
        #pragma unroll
        for (int ee = 0; ee < 4; ++ee) {
            m[ee] = silu_f(m[ee] + b2_s[lane]);
            sm_s[wv][ee][lane] = m[ee];
            atomicAdd(&tot_msg[ra[ee] * 64 + lane], m[ee]);
        }

        // ---- layer 3: t = silu(msg @ wc1 + bc1)
        float t[4] = {0.f, 0.f, 0.f, 0.f};
        #pragma unroll
        for (int kg = 0; kg < 16; ++kg) {
            float mv[4][4];
            #pragma unroll
            for (int ee = 0; ee < 4; ++ee) {
                float4 v = *(const float4*)&sm_s[wv][ee][kg * 4];
                mv[ee][0] = v.x; mv[ee][1] = v.y; mv[ee][2] = v.z; mv[ee][3] = v.w;
            }
            #pragma unroll
            for (int i = 0; i < 4; ++i) {
                const float wvv = wc1_s[(kg * 4 + i) * 64 + lane];
                #pragma unroll
                for (int ee = 0; ee < 4; ++ee) t[ee] += mv[ee][i] * wvv;
            }
        }

        // ---- coord head: coord = <t, wc2> + bc2 (wave butterfly reduce)
        #pragma unroll
        for (int ee = 0; ee < 4; ++ee) {
            float p = silu_f(t[ee] + bc1_s[lane]) * wc2_s[lane];
            p += __shfl_xor(p, 32);
            p += __shfl_xor(p, 16);
            p += __shfl_xor(p, 8);
            p += __shfl_xor(p, 4);
            p += __shfl_xor(p, 2);
            p += __shfl_xor(p, 1);
            cmsg[ee] = p + bc2v;
        }

        // ---- f = rij * coord and degree, atomic into totf4[row] (4 comps)
        if (lane < 16) {
            const int ee = lane >> 2;
            const int ci = lane & 3;
            const float fx = (ee == 0) ? rxa[0] : (ee == 1) ? rxa[1] : (ee == 2) ? rxa[2] : rxa[3];
            const float fy = (ee == 0) ? rya[0] : (ee == 1) ? rya[1] : (ee == 2) ? rya[2] : rya[3];
            const float fz = (ee == 0) ? rza[0] : (ee == 1) ? rza[1] : (ee == 2) ? rza[2] : rza[3];
            const float cm = (ee == 0) ? cmsg[0] : (ee == 1) ? cmsg[1] : (ee == 2) ? cmsg[2] : cmsg[3];
            const int   rr = (ee == 0) ? ra[0] : (ee == 1) ? ra[1] : (ee == 2) ? ra[2] : ra[3];
            const float val = (ci == 0) ? fx * cm : (ci == 1) ? fy * cm : (ci == 2) ? fz * cm : 1.0f;
            atomicAdd(&totf4[rr * 4 + ci], val);
        }
    }
}

// ---------------------------------------------------------------- K3: nodes
__global__ __launch_bounds__(256) void node_kernel(
    const float* __restrict__ x, const float* __restrict__ h,
    const float* __restrict__ wn1, const float* __restrict__ bn1,
    const float* __restrict__ wn2, const float* __restrict__ bn2,
    const float* __restrict__ tot_msg, const float* __restrict__ totf4,
    float* __restrict__ out)
{
    __shared__ __align__(16) float wn1_s[128 * 64];
    __shared__ __align__(16) float wn2_s[64 * 64];
    __shared__ float bn1_s[64], bn2_s[64];
    __shared__ __align__(16) float nm_s[4][4][128];
    __shared__ __align__(16) float g_s[4][4][64];

    const int tid  = threadIdx.x;
    const int lane = tid & 63;
    const int wv   = __builtin_amdgcn_readfirstlane(tid >> 6);

    {
        const float4* s1 = (const float4*)wn1;
        float4* d1 = (float4*)wn1_s;
        for (int i = tid; i < 2048; i += 256) d1[i] = s1[i];
        const float4* s2 = (const float4*)wn2;
        float4* d2 = (float4*)wn2_s;
        for (int i = tid; i < 1024; i += 256) d2[i] = s2[i];
        if (tid < 64) { bn1_s[tid] = bn1[tid]; bn2_s[tid] = bn2[tid]; }
    }
    const int n0 = blockIdx.x * 16 + wv * 4;
    #pragma unroll
    for (int nn = 0; nn < 4; ++nn) {
        nm_s[wv][nn][lane]      = h[(n0 + nn) * 64 + lane];
        nm_s[wv][nn][64 + lane] = tot_msg[(n0 + nn) * 64 + lane];
    }
    __syncthreads();

    // layer 1: g = silu(nm @ wn1 + bn1)
    float acc[4] = {0.f, 0.f, 0.f, 0.f};
    #pragma unroll
    for (int kg = 0; kg < 32; ++kg) {
        float nv[4][4];
        #pragma unroll
        for (int nn = 0; nn < 4; ++nn) {
            float4 v = *(const float4*)&nm_s[wv][nn][kg * 4];
            nv[nn][0] = v.x; nv[nn][1] = v.y; nv[nn][2] = v.z; nv[nn][3] = v.w;
        }
        #pragma unroll
        for (int i = 0; i < 4; ++i) {
            const float wvv = wn1_s[(kg * 4 + i) * 64 + lane];
            #pragma unroll
            for (int nn = 0; nn < 4; ++nn) acc[nn] += nv[nn][i] * wvv;
        }
    }
    #pragma unroll
    for (int nn = 0; nn < 4; ++nn)
        g_s[wv][nn][lane] = silu_f(acc[nn] + bn1_s[lane]);

    // layer 2: h_new = g @ wn2 + bn2 (no activation)
    float acc2[4] = {0.f, 0.f, 0.f, 0.f};
    #pragma unroll
    for (int kg = 0; kg < 16; ++kg) {
        float gv[4][4];
        #pragma unroll
        for (int nn = 0; nn < 4; ++nn) {
            float4 v = *(const float4*)&g_s[wv][nn][kg * 4];
            gv[nn][0] = v.x; gv[nn][1] = v.y; gv[nn][2] = v.z; gv[nn][3] = v.w;
        }
        #pragma unroll
        for (int i = 0; i < 4; ++i) {
            const float wvv = wn2_s[(kg * 4 + i) * 64 + lane];
            #pragma unroll
            for (int nn = 0; nn < 4; ++nn) acc2[nn] += gv[nn][i] * wvv;
        }
    }
    float* out_h = out + N_NODES * 3;
    #pragma unroll
    for (int nn = 0; nn < 4; ++nn)
        out_h[(n0 + nn) * 64 + lane] = acc2[nn] + bn2_s[lane];

    // x_new = x + clamp(tot_f / max(deg,1), +-100): lanes 0..11 -> 4 nodes x 3
    if (lane < 12) {
        const int nn = lane / 3;
        const int ci = lane % 3;
        const int n  = n0 + nn;
        const float tot = totf4[n * 4 + ci];
        const float deg = totf4[n * 4 + 3];
        const float d   = fmaxf(deg, 1.0f);
        float v = tot / d;
        v = fminf(fmaxf(v, -100.0f), 100.0f);
        out[n * 3 + ci] = x[n * 3 + ci] + v;
    }
}

// ---------------------------------------------------------------- launcher
extern "C" void kernel_launch(void* const* d_in, const int* in_sizes, int n_in,
                              void* d_out, int out_size, void* d_ws, size_t ws_size,
                              hipStream_t stream) {
    const float* x        = (const float*)d_in[0];
    const float* h        = (const float*)d_in[1];
    const float* edge_fea = (const float*)d_in[2];
    const float* w1e      = (const float*)d_in[3];
    const float* b1e      = (const float*)d_in[4];
    const float* w2e      = (const float*)d_in[5];
    const float* b2e      = (const float*)d_in[6];
    const float* wc1      = (const float*)d_in[7];
    const float* bc1      = (const float*)d_in[8];
    const float* wc2      = (const float*)d_in[9];
    const float* bc2      = (const float*)d_in[10];
    const float* wn1      = (const float*)d_in[11];
    const float* bn1      = (const float*)d_in[12];
    const float* wn2      = (const float*)d_in[13];
    const float* bn2      = (const float*)d_in[14];
    const int*   row      = (const int*)d_in[15];
    const int*   col      = (const int*)d_in[16];
    float* out = (float*)d_out;

    // ws layout (floats): hA[N*64] | hB[N*64] | tot_msg[N*64] | totf4[N*4]
    float* ws      = (float*)d_ws;
    float* hA      = ws;
    float* hB      = ws + (size_t)N_NODES * 64;
    float* tot_msg = ws + (size_t)2 * N_NODES * 64;
    float* totf4   = ws + (size_t)3 * N_NODES * 64;

    hipMemsetAsync(tot_msg, 0, (size_t)(N_NODES * 64 + N_NODES * 4) * sizeof(float), stream);

    node_pre_kernel<<<N_NODES / 16, 256, 0, stream>>>(h, w1e, hA, hB);
    edge_kernel<<<2048, 256, 0, stream>>>(x, edge_fea, w1e, b1e, w2e, b2e,
                                          wc1, bc1, wc2, bc2, row, col,
                                          hA, hB, tot_msg, totf4);
    node_kernel<<<N_NODES / 16, 256, 0, stream>>>(x, h, wn1, bn1, wn2, bn2,
                                                  tot_msg, totf4, out);
}

// Round 3
// 421.390 us; speedup vs baseline: 1.4918x; 1.4918x over previous
//
#include <hip/hip_runtime.h>
#include <cstddef>

// EGNN layer. Round 3: round-2 MFMA structure + NaN-pad fix.
// N=50000 nodes, M=800000 edges, H=64, E=16, IN_E=145.
//
// Bug fixed vs round 2: layer-1 MFMA reads A-fragment k=0..31 but fea staging
// writes only k=0..15. Cols 16..31 held uninitialized LDS garbage on the first
// loop iteration; bf16 Inf/NaN patterns there give 0*Inf=NaN in the MFMA and
// poison the whole edge pipeline (clamp turns NaN into +-100 => absmax 101.25).
// Fix: zero the pad region per wave before the loop. Also add zero-cost
// compiler memory fences at LDS write->read handoffs.
//
// MFMA fragment layouts (gfx950, 16x16x32 bf16, verified learn_hip m89/m91):
//   A: lane holds A[m=lane&15][k=(lane>>4)*8 + j], j=0..7
//   B: lane holds B[k=(lane>>4)*8 + j][n=lane&15]
//   C/D: lane reg r holds D[row=(lane>>4)*4+r][col=lane&15]

#define N_NODES 50000
#define M_EDGES 800000

typedef __attribute__((ext_vector_type(8))) short bf16x8;
typedef __attribute__((ext_vector_type(4))) short bf16x4;
typedef __attribute__((ext_vector_type(4))) float f32x4;

__device__ __forceinline__ float silu_f(float v) {
    return v / (1.0f + __expf(-v));
}

__device__ __forceinline__ short f2bf(float f) {   // RNE float->bf16
    union { float f; unsigned u; } v; v.f = f;
    unsigned r = v.u + 0x7fffu + ((v.u >> 16) & 1u);
    return (short)(r >> 16);
}

#define LDS_FENCE() __asm__ volatile("" ::: "memory")

// ---------------------------------------------------------------- K1: hA/hB
__global__ __launch_bounds__(256) void node_pre_kernel(
    const float* __restrict__ h, const float* __restrict__ w1e,
    float* __restrict__ hA, float* __restrict__ hB)
{
    __shared__ __align__(16) float wa_s[64 * 64];
    __shared__ __align__(16) float wb_s[64 * 64];
    __shared__ __align__(16) float hs[4][4][64];

    const int tid  = threadIdx.x;
    const int lane = tid & 63;
    const int wv   = __builtin_amdgcn_readfirstlane(tid >> 6);

    {
        const float4* sa = (const float4*)(w1e + 64);
        const float4* sb = (const float4*)(w1e + 65 * 64);
        float4* da = (float4*)wa_s;
        float4* db = (float4*)wb_s;
        for (int i = tid; i < 1024; i += 256) { da[i] = sa[i]; db[i] = sb[i]; }
    }
    const int n0 = blockIdx.x * 16 + wv * 4;
    #pragma unroll
    for (int nn = 0; nn < 4; ++nn)
        hs[wv][nn][lane] = h[(n0 + nn) * 64 + lane];
    __syncthreads();

    float accA[4] = {0.f, 0.f, 0.f, 0.f};
    float accB[4] = {0.f, 0.f, 0.f, 0.f};
    #pragma unroll
    for (int kg = 0; kg < 16; ++kg) {
        float hv[4][4];
        #pragma unroll
        for (int nn = 0; nn < 4; ++nn) {
            float4 v = *(const float4*)&hs[wv][nn][kg * 4];
            hv[nn][0] = v.x; hv[nn][1] = v.y; hv[nn][2] = v.z; hv[nn][3] = v.w;
        }
        #pragma unroll
        for (int i = 0; i < 4; ++i) {
            const float wa = wa_s[(kg * 4 + i) * 64 + lane];
            const float wb = wb_s[(kg * 4 + i) * 64 + lane];
            #pragma unroll
            for (int nn = 0; nn < 4; ++nn) {
                accA[nn] += hv[nn][i] * wa;
                accB[nn] += hv[nn][i] * wb;
            }
        }
    }
    #pragma unroll
    for (int nn = 0; nn < 4; ++nn) {
        hA[(n0 + nn) * 64 + lane] = accA[nn];
        hB[(n0 + nn) * 64 + lane] = accB[nn];
    }
}

// ---------------------------------------------------------------- K2: edges
__global__ __launch_bounds__(256, 3) void edge_kernel(
    const float* __restrict__ x, const float* __restrict__ edge_fea,
    const float* __restrict__ w1e, const float* __restrict__ b1e,
    const float* __restrict__ w2e, const float* __restrict__ b2e,
    const float* __restrict__ wc1, const float* __restrict__ bc1,
    const float* __restrict__ wc2, const float* __restrict__ bc2,
    const int* __restrict__ row, const int* __restrict__ col,
    const float* __restrict__ hA, const float* __restrict__ hB,
    float* __restrict__ tot_msg, float* __restrict__ totf4)
{
    __shared__ __align__(16) short w2t_s[64 * 72];   // w2e transposed [n][k] bf16
    __shared__ __align__(16) short wc1t_s[64 * 72];  // wc1 transposed [n][k] bf16
    __shared__ __align__(16) short u_s[4][16 * 72];  // per-wave activation A-tile
    __shared__ float4 rs_s[4][16];                    // (dx,dy,dz,sq) per edge
    __shared__ int2   ri_s[4][16];                    // (row,col) per edge

    const int tid  = threadIdx.x;
    const int lane = tid & 63;
    const int wv   = __builtin_amdgcn_readfirstlane(tid >> 6);
    const int l15  = lane & 15;
    const int l4   = lane >> 4;

    // ---- stage transposed bf16 weights into LDS (once per block)
    for (int i = tid; i < 4096; i += 256) {
        const int k = i >> 6, n = i & 63;
        w2t_s[n * 72 + k]  = f2bf(w2e[i]);
        wc1t_s[n * 72 + k] = f2bf(wc1[i]);
    }
    __syncthreads();

    // ---- per-lane register fragments and constants
    bf16x8 bw2f[4][2], bwc1f[4][2], bw1cf[4];
    float b1r[4], w10r[4], b2r[4], bc1r[4], wc2r[4];
    #pragma unroll
    for (int t = 0; t < 4; ++t) {
        #pragma unroll
        for (int s = 0; s < 2; ++s) {
            bw2f[t][s]  = *(const bf16x8*)&w2t_s[(t * 16 + l15) * 72 + s * 32 + l4 * 8];
            bwc1f[t][s] = *(const bf16x8*)&wc1t_s[(t * 16 + l15) * 72 + s * 32 + l4 * 8];
        }
        bf16x8 wf;
        #pragma unroll
        for (int b = 0; b < 8; ++b) {
            const int k = l4 * 8 + b;
            wf[b] = (k < 16) ? f2bf(w1e[(129 + k) * 64 + t * 16 + l15]) : (short)0;
        }
        bw1cf[t] = wf;
        b1r[t]  = b1e[t * 16 + l15];
        w10r[t] = w1e[t * 16 + l15];
        b2r[t]  = b2e[t * 16 + l15];
        bc1r[t] = bc1[t * 16 + l15];
        wc2r[t] = wc2[t * 16 + l15];
    }
    const float bc2v = bc2[0];
    short* const us = &u_s[wv][0];
    const f32x4 zf = {0.f, 0.f, 0.f, 0.f};

    // ---- NaN-pad fix: zero cols 16..31 of all 16 A-tile rows (per wave).
    // These k-slots multiply a zero B-fragment, but 0*Inf/NaN = NaN, so the
    // garbage there must be finite. One bf16x4 of zeros per lane covers it.
    {
        const bf16x4 z4 = {0, 0, 0, 0};
        *(bf16x4*)&us[(lane >> 2) * 72 + 16 + (lane & 3) * 4] = z4;
    }
    LDS_FENCE();

    for (int g = blockIdx.x; g < M_EDGES / 64; g += gridDim.x) {
        const int ebase = g * 64 + wv * 16;

        // ---- stash indices, rij, sq (one edge per lane, 16 lanes)
        if (lane < 16) {
            const int e = ebase + lane;
            const int r = row[e], c = col[e];
            ri_s[wv][lane] = make_int2(r, c);
            const float dx = x[r * 3 + 0] - x[c * 3 + 0];
            const float dy = x[r * 3 + 1] - x[c * 3 + 1];
            const float dz = x[r * 3 + 2] - x[c * 3 + 2];
            rs_s[wv][lane] = make_float4(dx, dy, dz, dx * dx + dy * dy + dz * dz);
        }

        // ---- stage fea tile into A-layout rows (cols 0..15)
        {
            const float4 fv = *(const float4*)(edge_fea + (size_t)ebase * 16 + lane * 4);
            bf16x4 b;
            b[0] = f2bf(fv.x); b[1] = f2bf(fv.y); b[2] = f2bf(fv.z); b[3] = f2bf(fv.w);
            *(bf16x4*)&us[(lane >> 2) * 72 + (lane & 3) * 4] = b;
        }
        LDS_FENCE();

        // ---- layer1 partial: fea @ w1c via MFMA (B rows k>=16 are zero)
        f32x4 acc1[4];
        {
            const bf16x8 af = *(const bf16x8*)&us[l15 * 72 + l4 * 8];
            #pragma unroll
            for (int t = 0; t < 4; ++t)
                acc1[t] = __builtin_amdgcn_mfma_f32_16x16x32_bf16(af, bw1cf[t], zf, 0, 0, 0);
        }

        // ---- per-lane C-row edge data
        int rIdx[4], cIdx[4]; float sqv[4];
        #pragma unroll
        for (int r = 0; r < 4; ++r) {
            const int2 rc = ri_s[wv][l4 * 4 + r];
            rIdx[r] = rc.x; cIdx[r] = rc.y;
            sqv[r] = rs_s[wv][l4 * 4 + r].w;
        }

        // ---- finish layer1: gathered hA/hB + sq*w1r0 + b1, silu, store u1 bf16
        #pragma unroll
        for (int r = 0; r < 4; ++r) {
            #pragma unroll
            for (int t = 0; t < 4; ++t) {
                const float hv = hA[(size_t)rIdx[r] * 64 + t * 16 + l15]
                               + hB[(size_t)cIdx[r] * 64 + t * 16 + l15];
                const float pre = acc1[t][r] + hv + sqv[r] * w10r[t] + b1r[t];
                us[(l4 * 4 + r) * 72 + t * 16 + l15] = f2bf(silu_f(pre));
            }
        }
        LDS_FENCE();

        // ---- layer2: msg = silu(u1 @ w2e + b2)
        f32x4 acc2[4];
        {
            const bf16x8 a0 = *(const bf16x8*)&us[l15 * 72 + l4 * 8];
            const bf16x8 a1 = *(const bf16x8*)&us[l15 * 72 + 32 + l4 * 8];
            #pragma unroll
            for (int t = 0; t < 4; ++t) {
                acc2[t] = __builtin_amdgcn_mfma_f32_16x16x32_bf16(a0, bw2f[t][0], zf, 0, 0, 0);
                acc2[t] = __builtin_amdgcn_mfma_f32_16x16x32_bf16(a1, bw2f[t][1], acc2[t], 0, 0, 0);
            }
        }
        float msg[4][4];
        #pragma unroll
        for (int t = 0; t < 4; ++t)
            #pragma unroll
            for (int r = 0; r < 4; ++r)
                msg[t][r] = silu_f(acc2[t][r] + b2r[t]);

        // atomics into tot_msg[row], and store msg bf16 back into A-tile
        #pragma unroll
        for (int r = 0; r < 4; ++r)
            #pragma unroll
            for (int t = 0; t < 4; ++t)
                atomicAdd(&tot_msg[(size_t)rIdx[r] * 64 + t * 16 + l15], msg[t][r]);
        #pragma unroll
        for (int r = 0; r < 4; ++r)
            #pragma unroll
            for (int t = 0; t < 4; ++t)
                us[(l4 * 4 + r) * 72 + t * 16 + l15] = f2bf(msg[t][r]);
        LDS_FENCE();

        // ---- layer3: t = silu(msg @ wc1 + bc1); coord partials
        f32x4 acc3[4];
        {
            const bf16x8 a0 = *(const bf16x8*)&us[l15 * 72 + l4 * 8];
            const bf16x8 a1 = *(const bf16x8*)&us[l15 * 72 + 32 + l4 * 8];
            #pragma unroll
            for (int t = 0; t < 4; ++t) {
                acc3[t] = __builtin_amdgcn_mfma_f32_16x16x32_bf16(a0, bwc1f[t][0], zf, 0, 0, 0);
                acc3[t] = __builtin_amdgcn_mfma_f32_16x16x32_bf16(a1, bwc1f[t][1], acc3[t], 0, 0, 0);
            }
        }
        float p[4] = {0.f, 0.f, 0.f, 0.f};
        #pragma unroll
        for (int t = 0; t < 4; ++t)
            #pragma unroll
            for (int r = 0; r < 4; ++r)
                p[r] += silu_f(acc3[t][r] + bc1r[t]) * wc2r[t];
        #pragma unroll
        for (int r = 0; r < 4; ++r) {
            p[r] += __shfl_xor(p[r], 1);
            p[r] += __shfl_xor(p[r], 2);
            p[r] += __shfl_xor(p[r], 4);
            p[r] += __shfl_xor(p[r], 8);
        }

        // ---- f = rij*coord (+deg) atomic: lane -> (edge=lane>>2, comp=lane&3)
        {
            const int el = lane >> 2, ci = lane & 3;
            const int rsel = el & 3;
            float cval = (rsel == 0) ? p[0] : (rsel == 1) ? p[1] : (rsel == 2) ? p[2] : p[3];
            cval += bc2v;
            const float4 rv = rs_s[wv][el];
            const int ridx = ri_s[wv][el].x;
            const float val = (ci == 0) ? rv.x * cval
                            : (ci == 1) ? rv.y * cval
                            : (ci == 2) ? rv.z * cval : 1.0f;
            atomicAdd(&totf4[(size_t)ridx * 4 + ci], val);
        }
    }
}

// ---------------------------------------------------------------- K3: nodes
__global__ __launch_bounds__(256) void node_kernel(
    const float* __restrict__ x, const float* __restrict__ h,
    const float* __restrict__ wn1, const float* __restrict__ bn1,
    const float* __restrict__ wn2, const float* __restrict__ bn2,
    const float* __restrict__ tot_msg, const float* __restrict__ totf4,
    float* __restrict__ out)
{
    __shared__ __align__(16) float wn1_s[128 * 64];
    __shared__ __align__(16) float wn2_s[64 * 64];
    __shared__ float bn1_s[64], bn2_s[64];
    __shared__ __align__(16) float nm_s[4][4][128];
    __shared__ __align__(16) float g_s[4][4][64];

    const int tid  = threadIdx.x;
    const int lane = tid & 63;
    const int wv   = __builtin_amdgcn_readfirstlane(tid >> 6);

    {
        const float4* s1 = (const float4*)wn1;
        float4* d1 = (float4*)wn1_s;
        for (int i = tid; i < 2048; i += 256) d1[i] = s1[i];
        const float4* s2 = (const float4*)wn2;
        float4* d2 = (float4*)wn2_s;
        for (int i = tid; i < 1024; i += 256) d2[i] = s2[i];
        if (tid < 64) { bn1_s[tid] = bn1[tid]; bn2_s[tid] = bn2[tid]; }
    }
    const int n0 = blockIdx.x * 16 + wv * 4;
    #pragma unroll
    for (int nn = 0; nn < 4; ++nn) {
        nm_s[wv][nn][lane]      = h[(n0 + nn) * 64 + lane];
        nm_s[wv][nn][64 + lane] = tot_msg[(n0 + nn) * 64 + lane];
    }
    __syncthreads();

    float acc[4] = {0.f, 0.f, 0.f, 0.f};
    #pragma unroll
    for (int kg = 0; kg < 32; ++kg) {
        float nv[4][4];
        #pragma unroll
        for (int nn = 0; nn < 4; ++nn) {
            float4 v = *(const float4*)&nm_s[wv][nn][kg * 4];
            nv[nn][0] = v.x; nv[nn][1] = v.y; nv[nn][2] = v.z; nv[nn][3] = v.w;
        }
        #pragma unroll
        for (int i = 0; i < 4; ++i) {
            const float wvv = wn1_s[(kg * 4 + i) * 64 + lane];
            #pragma unroll
            for (int nn = 0; nn < 4; ++nn) acc[nn] += nv[nn][i] * wvv;
        }
    }
    #pragma unroll
    for (int nn = 0; nn < 4; ++nn)
        g_s[wv][nn][lane] = silu_f(acc[nn] + bn1_s[lane]);
    LDS_FENCE();

    float acc2[4] = {0.f, 0.f, 0.f, 0.f};
    #pragma unroll
    for (int kg = 0; kg < 16; ++kg) {
        float gv[4][4];
        #pragma unroll
        for (int nn = 0; nn < 4; ++nn) {
            float4 v = *(const float4*)&g_s[wv][nn][kg * 4];
            gv[nn][0] = v.x; gv[nn][1] = v.y; gv[nn][2] = v.z; gv[nn][3] = v.w;
        }
        #pragma unroll
        for (int i = 0; i < 4; ++i) {
            const float wvv = wn2_s[(kg * 4 + i) * 64 + lane];
            #pragma unroll
            for (int nn = 0; nn < 4; ++nn) acc2[nn] += gv[nn][i] * wvv;
        }
    }
    float* out_h = out + N_NODES * 3;
    #pragma unroll
    for (int nn = 0; nn < 4; ++nn)
        out_h[(n0 + nn) * 64 + lane] = acc2[nn] + bn2_s[lane];

    if (lane < 12) {
        const int nn = lane / 3;
        const int ci = lane % 3;
        const int n  = n0 + nn;
        const float tot = totf4[n * 4 + ci];
        const float deg = totf4[n * 4 + 3];
        const float d   = fmaxf(deg, 1.0f);
        float v = tot / d;
        v = fminf(fmaxf(v, -100.0f), 100.0f);
        out[n * 3 + ci] = x[n * 3 + ci] + v;
    }
}

// ---------------------------------------------------------------- launcher
extern "C" void kernel_launch(void* const* d_in, const int* in_sizes, int n_in,
                              void* d_out, int out_size, void* d_ws, size_t ws_size,
                              hipStream_t stream) {
    const float* x        = (const float*)d_in[0];
    const float* h        = (const float*)d_in[1];
    const float* edge_fea = (const float*)d_in[2];
    const float* w1e      = (const float*)d_in[3];
    const float* b1e      = (const float*)d_in[4];
    const float* w2e      = (const float*)d_in[5];
    const float* b2e      = (const float*)d_in[6];
    const float* wc1      = (const float*)d_in[7];
    const float* bc1      = (const float*)d_in[8];
    const float* wc2      = (const float*)d_in[9];
    const float* bc2      = (const float*)d_in[10];
    const float* wn1      = (const float*)d_in[11];
    const float* bn1      = (const float*)d_in[12];
    const float* wn2      = (const float*)d_in[13];
    const float* bn2      = (const float*)d_in[14];
    const int*   row      = (const int*)d_in[15];
    const int*   col      = (const int*)d_in[16];
    float* out = (float*)d_out;

    float* ws      = (float*)d_ws;
    float* hA      = ws;
    float* hB      = ws + (size_t)N_NODES * 64;
    float* tot_msg = ws + (size_t)2 * N_NODES * 64;
    float* totf4   = ws + (size_t)3 * N_NODES * 64;

    hipMemsetAsync(tot_msg, 0, (size_t)(N_NODES * 64 + N_NODES * 4) * sizeof(float), stream);

    node_pre_kernel<<<N_NODES / 16, 256, 0, stream>>>(h, w1e, hA, hB);
    edge_kernel<<<2048, 256, 0, stream>>>(x, edge_fea, w1e, b1e, w2e, b2e,
                                          wc1, bc1, wc2, bc2, row, col,
                                          hA, hB, tot_msg, totf4);
    node_kernel<<<N_NODES / 16, 256, 0, stream>>>(x, h, wn1, bn1, wn2, bn2,
                                                  tot_msg, totf4, out);
}